// Round 3
// baseline (69814.941 us; speedup 1.0000x reference)
//
#include <hip/hip_runtime.h>
#include <hip/hip_bf16.h>

// L=2, B=128, T=512, D=64, F=512
#define FDIM   512
#define BATCH  128
#define TSTEPS 512
#define GDIM   2048
#define NPHASES (2*TSTEPS)
#define WGS_PER_GROUP 32

typedef __attribute__((ext_vector_type(8))) short bf16x8;   // 8 bf16 (4 VGPR) MFMA A/B frag
typedef __attribute__((ext_vector_type(4))) float f32x4;    // MFMA C/D frag

__device__ __forceinline__ ushort f32_to_bf16(float v) {
    union { float f; unsigned u; } c; c.f = v;
    unsigned b = c.u;
    return (ushort)((b + 0x7FFFu + ((b >> 16) & 1u)) >> 16);   // RNE
}
__device__ __forceinline__ float sigmoidf_(float x) { return 1.0f / (1.0f + expf(-x)); }

// ---------------------------------------------------------------------------
// One-time: weights -> bf16 concat layout wcat[L][2048][1024] (Wih row || Whh row),
// combined bias bc[L][2048].
// ---------------------------------------------------------------------------
__global__ __launch_bounds__(256) void convert_weights(
    const float* __restrict__ Wih0, const float* __restrict__ Whh0,
    const float* __restrict__ Wih1, const float* __restrict__ Whh1,
    const float* __restrict__ bih0, const float* __restrict__ bhh0,
    const float* __restrict__ bih1, const float* __restrict__ bhh1,
    ushort* __restrict__ wcat, float* __restrict__ bc)
{
    int idx = blockIdx.x * 256 + threadIdx.x;          // covers 2*2048*1024
    if (idx < 2 * GDIM * 1024) {
        int kk = idx & 1023;
        int r  = (idx >> 10) & 2047;
        int L  = idx >> 21;
        const float* Wih = L ? Wih1 : Wih0;
        const float* Whh = L ? Whh1 : Whh0;
        float v = (kk < 512) ? Wih[(size_t)r * 512 + kk] : Whh[(size_t)r * 512 + (kk - 512)];
        wcat[idx] = f32_to_bf16(v);
    }
    if (idx < 2 * GDIM) {
        int L = idx >> 11, r = idx & 2047;
        bc[idx] = L ? (bih1[r] + bhh1[r]) : (bih0[r] + bhh0[r]);
    }
}

// ---------------------------------------------------------------------------
// Group barrier: fresh counter per phase (no sense reversal). Agent-scope
// release/acquire via __threadfence so correctness is placement-independent.
// ---------------------------------------------------------------------------
__device__ __forceinline__ void group_barrier(unsigned* c, int tid) {
    __threadfence();            // release: drain my stores to device scope
    __syncthreads();            // all threads of WG fenced
    if (tid == 0) {
        __hip_atomic_fetch_add(c, 1u, __ATOMIC_RELAXED, __HIP_MEMORY_SCOPE_AGENT);
        while (__hip_atomic_load(c, __ATOMIC_RELAXED, __HIP_MEMORY_SCOPE_AGENT) < WGS_PER_GROUP)
            __builtin_amdgcn_s_sleep(1);
    }
    __syncthreads();
    __threadfence();            // acquire: invalidate stale cached lines
}

// ---------------------------------------------------------------------------
// Persistent 2-layer LSTM. 256 WGs x 512 threads.
//   WG = (g = blockIdx&7 batch group of 16 rows, ft = blockIdx>>3 f-tile of 16 cols)
//   waves 0-3: layer 0, waves 4-7: layer 1; wave kq = K-quarter of [inp(512)||h(512)]
//   Weights: 128 VGPR of B-frags per wave (loaded once). c-state: 1 reg/thread.
//   hst[L][par][128][512] bf16; per phase: group barrier -> A-frags from global
//   -> 32 MFMA -> LDS 4-way K-reduce -> gate nonlin -> publish h tile.
// ---------------------------------------------------------------------------
__global__ __launch_bounds__(512, 2) void lstm_persistent(
    const float* __restrict__ x,      // (2,128,64)
    const float* __restrict__ Winit,  // (512,64)
    const float* __restrict__ binit,  // (512,)
    const float* __restrict__ lastf,  // (128,512)
    const ushort* __restrict__ wcat,  // [2][2048][1024] bf16
    const float* __restrict__ bc,     // [2][2048]
    ushort* __restrict__ hst,         // [2][2][128][512] bf16
    ushort* __restrict__ lfbuf,       // [128][512] bf16
    unsigned* __restrict__ cnt,       // [NPHASES+1][8]
    float* __restrict__ out)          // (512,128,512) == raw reshape target
{
    const int tid  = threadIdx.x;
    const int lane = tid & 63;
    const int wave = tid >> 6;        // 0..7
    const int myL  = wave >> 2;       // layer this wave serves
    const int kq   = wave & 3;        // K-quarter
    const int g    = blockIdx.x & 7;  // batch group (XCD-aligned)
    const int ft   = blockIdx.x >> 3; // feature tile 0..31

    const int r16 = (tid >> 4) & 15;  // epilogue batch row within group
    const int cc  = tid & 15;         // epilogue f col within tile
    const int myB = g * 16 + r16;
    const int myF = ft * 16 + cc;

    __shared__ float part[4][4][16][16];   // [kq][gate][fcol][brow]

    // ---- prologue: initial c/h for (myL,myB,myF); lf convert; bias; weight frags ----
    float c_reg;
    {
        const float* xr = x + ((size_t)myL * BATCH + myB) * 64;
        const float* wr = Winit + (size_t)myF * 64;
        float s = binit[myF];
        #pragma unroll
        for (int k = 0; k < 64; ++k) s += xr[k] * wr[k];
        c_reg = s;
        hst[(((size_t)myL * 2 + 1) * BATCH + myB) * FDIM + myF] = f32_to_bf16(s);
    }
    for (int i = tid; i < 16 * FDIM; i += 512) {       // group's 16 lf rows
        int rr = i >> 9, ff = i & 511;
        int b = g * 16 + rr;
        lfbuf[(size_t)b * FDIM + ff] = f32_to_bf16(lastf[(size_t)b * FDIM + ff]);
    }
    float bias[4];
    #pragma unroll
    for (int ct = 0; ct < 4; ++ct) bias[ct] = bc[myL * GDIM + ct * 512 + myF];

    bf16x8 bw[4][8];                                   // 128 VGPR of weights
    {
        const int wl = lane & 15, kg = lane >> 4;
        #pragma unroll
        for (int ct = 0; ct < 4; ++ct) {
            const ushort* base = wcat + ((size_t)myL * GDIM + ct * 512 + ft * 16 + wl) * 1024;
            #pragma unroll
            for (int ks = 0; ks < 8; ++ks)
                bw[ct][ks] = *reinterpret_cast<const bf16x8*>(base + kq * 256 + ks * 32 + kg * 8);
        }
    }

    group_barrier(&cnt[g], tid);                       // group init complete

    // ---- 1024 serial phases ----
    for (int ph = 0; ph < NPHASES; ++ph) {
        const int L = ph & 1;
        const int t = ph >> 1;
        const int parW = t & 1, parR = parW ^ 1;
        if (myL == L) {
            const ushort* srcInp = (L == 0)
                ? (t == 0 ? lfbuf : hst + (size_t)(1 * 2 + parR) * BATCH * FDIM)
                : (hst + (size_t)(0 * 2 + parW) * BATCH * FDIM);
            const ushort* srcH = hst + (size_t)(L * 2 + parR) * BATCH * FDIM;
            const ushort* srcA = (kq < 2) ? srcInp : srcH;
            const int rA = lane & 15, kg = lane >> 4;
            const ushort* arow = srcA + (size_t)(g * 16 + rA) * FDIM + (kq & 1) * 256 + kg * 8;

            bf16x8 af[8];
            #pragma unroll
            for (int ks = 0; ks < 8; ++ks)
                af[ks] = *reinterpret_cast<const bf16x8*>(arow + ks * 32);

            f32x4 acc[4] = {{0,0,0,0},{0,0,0,0},{0,0,0,0},{0,0,0,0}};
            #pragma unroll
            for (int ks = 0; ks < 8; ++ks) {
                #pragma unroll
                for (int ct = 0; ct < 4; ++ct)
                    acc[ct] = __builtin_amdgcn_mfma_f32_16x16x32_bf16(af[ks], bw[ct][ks], acc[ct], 0, 0, 0);
            }
            const int n = lane & 15, q = lane >> 4;    // C layout: m=(q*4+j) batch, n fcol
            #pragma unroll
            for (int ct = 0; ct < 4; ++ct)
                *reinterpret_cast<f32x4*>(&part[kq][ct][n][q * 4]) = acc[ct];
        }
        __syncthreads();
        if (myL == L) {
            float gate[4];
            #pragma unroll
            for (int ct = 0; ct < 4; ++ct) {
                float s = bias[ct];
                #pragma unroll
                for (int k2 = 0; k2 < 4; ++k2) s += part[k2][ct][cc][r16];
                gate[ct] = s;
            }
            float ig = sigmoidf_(gate[0]);
            float fg = sigmoidf_(gate[1]);
            float gg = tanhf(gate[2]);
            float og = sigmoidf_(gate[3]);
            float cn = fg * c_reg + ig * gg;
            float hn = og * tanhf(cn);
            c_reg = cn;
            hst[(((size_t)L * 2 + parW) * BATCH + myB) * FDIM + myF] = f32_to_bf16(hn);
            if (L == 1) out[((size_t)t * BATCH + myB) * FDIM + myF] = hn;
        }
        group_barrier(&cnt[(ph + 1) * 8 + g], tid);
    }
}

// ---------------------------------------------------------------------------
extern "C" void kernel_launch(void* const* d_in, const int* in_sizes, int n_in,
                              void* d_out, int out_size, void* d_ws, size_t ws_size,
                              hipStream_t stream)
{
    const float* x      = (const float*)d_in[0];
    const float* lastf  = (const float*)d_in[1];
    const float* W_init = (const float*)d_in[2];
    const float* b_init = (const float*)d_in[3];
    const float* W_ih0  = (const float*)d_in[4];
    const float* W_hh0  = (const float*)d_in[5];
    const float* b_ih0  = (const float*)d_in[6];
    const float* b_hh0  = (const float*)d_in[7];
    const float* W_ih1  = (const float*)d_in[8];
    const float* W_hh1  = (const float*)d_in[9];
    const float* b_ih1  = (const float*)d_in[10];
    const float* b_hh1  = (const float*)d_in[11];
    // d_in[12..13] = W_out/b_out: dead code in the reference.
    float* out = (float*)d_out;

    char* ws = (char*)d_ws;
    size_t off = 0;
    ushort*   wcat  = (ushort*)(ws + off);   off += (size_t)2 * GDIM * 1024 * 2;   // 8 MB
    float*    bcb   = (float*)(ws + off);    off += (size_t)2 * GDIM * 4;          // 16 KB
    ushort*   hstb  = (ushort*)(ws + off);   off += (size_t)2 * 2 * BATCH * FDIM * 2; // 512 KB
    ushort*   lfb   = (ushort*)(ws + off);   off += (size_t)BATCH * FDIM * 2;      // 128 KB
    unsigned* cnt   = (unsigned*)(ws + off); off += (size_t)(NPHASES + 1) * 8 * 4; // 33 KB

    hipMemsetAsync(cnt, 0, (size_t)(NPHASES + 1) * 8 * 4, stream);

    convert_weights<<<(2 * GDIM * 1024 + 255) / 256, 256, 0, stream>>>(
        W_ih0, W_hh0, W_ih1, W_hh1, b_ih0, b_hh0, b_ih1, b_hh1, wcat, bcb);

    lstm_persistent<<<256, 512, 0, stream>>>(
        x, W_init, b_init, lastf, wcat, bcb, hstb, lfb, cnt, out);
}

// Round 4
// 3024.475 us; speedup vs baseline: 23.0833x; 23.0833x over previous
//
#include <hip/hip_runtime.h>
#include <hip/hip_bf16.h>

// L=2, B=128, T=512, D=64, F=512
#define FDIM   512
#define BATCH  128
#define TSTEPS 512
#define GDIM   2048
#define NPH    (2*TSTEPS)

typedef __attribute__((ext_vector_type(8))) short bf16x8;   // 8 bf16 (4 VGPR) MFMA A/B frag
typedef __attribute__((ext_vector_type(4))) float f32x4;    // MFMA C/D frag

union AfU { bf16x8 v; unsigned long long q[2]; };

__device__ __forceinline__ ushort f32_to_bf16(float v) {
    union { float f; unsigned u; } c; c.f = v;
    unsigned b = c.u;
    return (ushort)((b + 0x7FFFu + ((b >> 16) & 1u)) >> 16);   // RNE
}
__device__ __forceinline__ float sigmoidf_(float x) { return 1.0f / (1.0f + expf(-x)); }

// Relaxed agent-scope (device-coherent, LLC-serialized) accesses. These emit
// sc0/sc1-flagged loads/stores: bypass per-XCD L1/L2 (no stale hits, no dirty
// lines) -> no cache-wide fences needed anywhere.
__device__ __forceinline__ unsigned long long aload64(const unsigned long long* p) {
    return __hip_atomic_load(p, __ATOMIC_RELAXED, __HIP_MEMORY_SCOPE_AGENT);
}
__device__ __forceinline__ unsigned aload32(const unsigned* p) {
    return __hip_atomic_load(p, __ATOMIC_RELAXED, __HIP_MEMORY_SCOPE_AGENT);
}
__device__ __forceinline__ void astore32(unsigned* p, unsigned v) {
    __hip_atomic_store(p, v, __ATOMIC_RELAXED, __HIP_MEMORY_SCOPE_AGENT);
}

// ---------------------------------------------------------------------------
// One-time: weights -> bf16 concat layout wcat[L][2048][1024] (Wih row || Whh row),
// combined bias bc[L][2048].
// ---------------------------------------------------------------------------
__global__ __launch_bounds__(256) void convert_weights(
    const float* __restrict__ Wih0, const float* __restrict__ Whh0,
    const float* __restrict__ Wih1, const float* __restrict__ Whh1,
    const float* __restrict__ bih0, const float* __restrict__ bhh0,
    const float* __restrict__ bih1, const float* __restrict__ bhh1,
    ushort* __restrict__ wcat, float* __restrict__ bc)
{
    int idx = blockIdx.x * 256 + threadIdx.x;          // covers 2*2048*1024
    if (idx < 2 * GDIM * 1024) {
        int kk = idx & 1023;
        int r  = (idx >> 10) & 2047;
        int L  = idx >> 21;
        const float* Wih = L ? Wih1 : Wih0;
        const float* Whh = L ? Whh1 : Whh0;
        float v = (kk < 512) ? Wih[(size_t)r * 512 + kk] : Whh[(size_t)r * 512 + (kk - 512)];
        wcat[idx] = f32_to_bf16(v);
    }
    if (idx < 2 * GDIM) {
        int L = idx >> 11, r = idx & 2047;
        bc[idx] = L ? (bih1[r] + bhh1[r]) : (bih0[r] + bhh0[r]);
    }
}

// ---------------------------------------------------------------------------
// Persistent 2-layer LSTM. 256 WGs x 512 threads, 1 WG/CU (VGPR-bound).
//   WG = (g = blockIdx&7: batch group of 16 rows [XCD-heuristic], ft: 16 f-cols)
//   waves 0-3 layer 0, waves 4-7 layer 1; wave kq = K-quarter of [inp||h].
//   Weights: bw[4][8] = 128 VGPR/lane, asm-pinned (no remat). c: 1 reg/thread.
//   Sync per phase: per-WG monotonic flag slot (store-only), wave0 polls the
//   group's 32 slots with one 32-lane vector load; h exchanged via relaxed
//   agent-scope (write-through LLC) accesses; __syncthreads' vmcnt(0) drain
//   orders h-stores before the flag store. No RMW atomics, no cache fences.
// ---------------------------------------------------------------------------
__global__ __launch_bounds__(512, 2) void lstm_persistent(
    const float* __restrict__ x,      // (2,128,64)
    const float* __restrict__ Winit,  // (512,64)
    const float* __restrict__ binit,  // (512,)
    const float* __restrict__ lastf,  // (128,512)
    const ushort* __restrict__ wcat,  // [2][2048][1024] bf16
    const float* __restrict__ bc,     // [2][2048]
    ushort* __restrict__ hst,         // [2][2][128][512] bf16 (slot = t&1; init slot 1)
    ushort* __restrict__ lfbuf,       // [128][512] bf16
    unsigned* __restrict__ flags,     // [256] : per-WG completed-phase count + 1
    float* __restrict__ out)          // (512,128,512) raw-reshape target
{
    const int tid  = threadIdx.x;
    const int lane = tid & 63;
    const int wave = tid >> 6;        // 0..7
    const int myL  = wave >> 2;       // layer this wave serves
    const int kq   = wave & 3;        // K-quarter of [inp(512) || h(512)]
    const int g    = blockIdx.x & 7;  // batch group
    const int ft   = blockIdx.x >> 3; // feature tile 0..31

    const int r16 = (tid >> 4) & 15;  // epilogue batch row within group
    const int cc  = tid & 15;         // epilogue f col within tile
    const int myB = g * 16 + r16;
    const int myF = ft * 16 + cc;

    __shared__ float part[4][4][16][16];   // [kq][gate][m=batch][n=fcol]

    // ---- prologue: initial c/h, lf convert, bias, pinned weight frags ----
    float c_reg;
    {
        const float* xr = x + ((size_t)myL * BATCH + myB) * 64;
        const float* wr = Winit + (size_t)myF * 64;
        float s = binit[myF];
        #pragma unroll
        for (int k = 0; k < 64; ++k) s += xr[k] * wr[k];
        c_reg = s;
        unsigned hv = f32_to_bf16(s);
        unsigned up = (unsigned)__shfl_xor((int)hv, 1);
        if (!(cc & 1))
            astore32((unsigned*)(hst + (((size_t)myL * 2 + 1) * BATCH + myB) * FDIM + myF),
                     hv | (up << 16));
    }
    if (myL == 0) {
        float v = lastf[(size_t)myB * FDIM + myF];
        unsigned hv = f32_to_bf16(v);
        unsigned up = (unsigned)__shfl_xor((int)hv, 1);
        if (!(cc & 1))
            astore32((unsigned*)(lfbuf + (size_t)myB * FDIM + myF), hv | (up << 16));
    }
    float bias[4];
    #pragma unroll
    for (int ct = 0; ct < 4; ++ct) bias[ct] = bc[myL * GDIM + ct * FDIM + myF];

    bf16x8 bw[4][8];                                   // 128 VGPR of weights
    {
        const int wl = lane & 15, kg = lane >> 4;
        #pragma unroll
        for (int ct = 0; ct < 4; ++ct) {
            const ushort* base = wcat + ((size_t)myL * GDIM + ct * FDIM + ft * 16 + wl) * 1024
                               + kq * 256 + kg * 8;
            #pragma unroll
            for (int ks = 0; ks < 8; ++ks)
                bw[ct][ks] = *reinterpret_cast<const bf16x8*>(base + ks * 32);
        }
    }
    // Pin: after this, rematerializing the loads would be illegal.
    #pragma unroll
    for (int ct = 0; ct < 4; ++ct)
        #pragma unroll
        for (int ks = 0; ks < 8; ++ks)
            asm volatile("" : "+v"(bw[ct][ks]));

    __syncthreads();                                   // drains the init stores
    if (tid == 0) astore32(&flags[g * 32 + ft], 1u);   // "0 phases complete"

    const int rA = lane & 15, kg = lane >> 4;

    // ---- 1024 serial phases ----
    for (int ph = 0; ph < NPH; ++ph) {
        const int L = ph & 1;
        const int t = ph >> 1;
        const bool active = (myL == L);

        const ushort* srcInp = (L == 0)
            ? (t == 0 ? lfbuf : hst + (size_t)(2 + ((t - 1) & 1)) * BATCH * FDIM)   // h1[t-1]
            : (hst + (size_t)(t & 1) * BATCH * FDIM);                               // h0[t]
        const ushort* srcOwn = hst + (size_t)(L * 2 + ((t - 1) & 1)) * BATCH * FDIM;
        const ushort* arow = ((kq < 2) ? srcInp : srcOwn)
                           + (size_t)(g * 16 + rA) * FDIM + (kq & 1) * 256 + kg * 8;

        bf16x8 af[8];
        // Own-h half is >=2 phases old -> visible since the PREVIOUS gate; load
        // before this phase's gate to overlap the poll. (ph==0: init not yet
        // gated -> load after.)
        const bool pre = active && (kq >= 2) && (ph > 0);
        if (pre) {
            #pragma unroll
            for (int ks = 0; ks < 8; ++ks) {
                AfU u;
                u.q[0] = aload64((const unsigned long long*)(arow + ks * 32));
                u.q[1] = aload64((const unsigned long long*)(arow + ks * 32) + 1);
                af[ks] = u.v;
            }
        }

        // gate: all 32 WGs of the group finished phase ph-1
        if (wave == 0) {
            const unsigned tgt = (unsigned)(ph + 1);
            for (;;) {
                unsigned v = (lane < 32) ? aload32(&flags[g * 32 + lane]) : tgt;
                if (__all((int)(v >= tgt))) break;
                __builtin_amdgcn_s_sleep(1);
            }
        }
        __syncthreads();

        if (active) {
            if (!pre) {
                #pragma unroll
                for (int ks = 0; ks < 8; ++ks) {
                    AfU u;
                    u.q[0] = aload64((const unsigned long long*)(arow + ks * 32));
                    u.q[1] = aload64((const unsigned long long*)(arow + ks * 32) + 1);
                    af[ks] = u.v;
                }
            }
            f32x4 acc[4] = {{0,0,0,0},{0,0,0,0},{0,0,0,0},{0,0,0,0}};
            #pragma unroll
            for (int ks = 0; ks < 8; ++ks) {
                #pragma unroll
                for (int ct = 0; ct < 4; ++ct)
                    acc[ct] = __builtin_amdgcn_mfma_f32_16x16x32_bf16(af[ks], bw[ct][ks], acc[ct], 0, 0, 0);
            }
            const int n = lane & 15, q = lane >> 4;    // C map: m=q*4+j (batch), n (fcol)
            #pragma unroll
            for (int ct = 0; ct < 4; ++ct)
                #pragma unroll
                for (int j = 0; j < 4; ++j)
                    part[kq][ct][q * 4 + j][n] = acc[ct][j];
        }
        __syncthreads();

        if (active) {
            float gate[4];
            #pragma unroll
            for (int ct = 0; ct < 4; ++ct)
                gate[ct] = bias[ct] + part[0][ct][r16][cc] + part[1][ct][r16][cc]
                         + part[2][ct][r16][cc] + part[3][ct][r16][cc];
            float ig = sigmoidf_(gate[0]);
            float fg = sigmoidf_(gate[1]);
            float gg = tanhf(gate[2]);
            float og = sigmoidf_(gate[3]);
            float cn = fg * c_reg + ig * gg;
            float hn = og * tanhf(cn);
            c_reg = cn;
            unsigned hv = f32_to_bf16(hn);
            unsigned up = (unsigned)__shfl_xor((int)hv, 1);
            if (!(cc & 1))
                astore32((unsigned*)(hst + ((size_t)(L * 2 + (t & 1)) * BATCH + myB) * FDIM + myF),
                         hv | (up << 16));
            if (L == 1) out[((size_t)t * BATCH + myB) * FDIM + myF] = hn;
        }
        __syncthreads();                               // drains h-stores (vmcnt0) WG-wide
        if (tid == 0) astore32(&flags[g * 32 + ft], (unsigned)(ph + 2));
    }
}

// ---------------------------------------------------------------------------
extern "C" void kernel_launch(void* const* d_in, const int* in_sizes, int n_in,
                              void* d_out, int out_size, void* d_ws, size_t ws_size,
                              hipStream_t stream)
{
    const float* x      = (const float*)d_in[0];
    const float* lastf  = (const float*)d_in[1];
    const float* W_init = (const float*)d_in[2];
    const float* b_init = (const float*)d_in[3];
    const float* W_ih0  = (const float*)d_in[4];
    const float* W_hh0  = (const float*)d_in[5];
    const float* b_ih0  = (const float*)d_in[6];
    const float* b_hh0  = (const float*)d_in[7];
    const float* W_ih1  = (const float*)d_in[8];
    const float* W_hh1  = (const float*)d_in[9];
    const float* b_ih1  = (const float*)d_in[10];
    const float* b_hh1  = (const float*)d_in[11];
    // d_in[12..13] = W_out/b_out: dead code in the reference.
    float* out = (float*)d_out;

    char* ws = (char*)d_ws;
    size_t off = 0;
    ushort*   wcat  = (ushort*)(ws + off);   off += (size_t)2 * GDIM * 1024 * 2;      // 8 MB
    float*    bcb   = (float*)(ws + off);    off += (size_t)2 * GDIM * 4;             // 16 KB
    ushort*   hstb  = (ushort*)(ws + off);   off += (size_t)2 * 2 * BATCH * FDIM * 2; // 512 KB
    ushort*   lfb   = (ushort*)(ws + off);   off += (size_t)BATCH * FDIM * 2;         // 128 KB
    unsigned* flags = (unsigned*)(ws + off); off += 256 * 4;                          // 1 KB

    hipMemsetAsync(flags, 0, 256 * 4, stream);

    convert_weights<<<(2 * GDIM * 1024 + 255) / 256, 256, 0, stream>>>(
        W_ih0, W_hh0, W_ih1, W_hh1, b_ih0, b_hh0, b_ih1, b_hh1, wcat, bcb);

    lstm_persistent<<<256, 512, 0, stream>>>(
        x, W_init, b_init, lastf, wcat, bcb, hstb, lfb, flags, out);
}